// Round 2
// baseline (5419.983 us; speedup 1.0000x reference)
//
#include <hip/hip_runtime.h>

// Problem constants (match reference)
#define KS_FULL 5
#define INC 64
#define OUTC 64
#define RUN_INC 48
#define RUN_OUTC 48
#define NPTS 200000
#define MPAIR 150000
#define K_RUN 27

// One thread per (k, m) pair. blockIdx.y = k so the 48x48 weight tile is
// block-uniform -> staged in LDS, read as uniform-address broadcasts.
__global__ __launch_bounds__(256) void conv_gather_scatter(
    const float* __restrict__ features,   // (N, 48)
    const float* __restrict__ kernel,     // (125, 64, 64)
    const int* __restrict__ in_idx,       // (27, M)
    const int* __restrict__ out_idx,      // (27, M)
    const int* __restrict__ mask,         // (27, M) bool -> int32 in harness
    float* __restrict__ out)              // (N, 48), pre-zeroed
{
    __shared__ float W[RUN_INC][RUN_OUTC];   // 9216 B

    const int k = blockIdx.y;                // 0..26
    const int a = k / 9;
    const int b = (k / 3) % 3;
    const int c = k % 3;
    const int kf = ((a + 1) * KS_FULL + (b + 1)) * KS_FULL + (c + 1);
    const float* __restrict__ Wsrc = kernel + (size_t)kf * (INC * OUTC);

    // stage 48x48 sub-tile of the 64x64 kernel slice into LDS
    for (int e = threadIdx.x; e < RUN_INC * RUN_OUTC; e += 256) {
        const int i = e / RUN_OUTC;
        const int o = e - i * RUN_OUTC;
        W[i][o] = Wsrc[i * OUTC + o];
    }
    __syncthreads();

    const int m = blockIdx.x * 256 + threadIdx.x;
    if (m >= MPAIR) return;
    const int pair = k * MPAIR + m;
    if (!mask[pair]) return;                 // inactive: no loads, no atomics

    const int in_row  = in_idx[pair];
    const int out_row = out_idx[pair];

    // gather feature row: 12 x float4 = 192 B (L2/L3-resident table)
    const float4* __restrict__ frow =
        (const float4*)(features + (size_t)in_row * RUN_INC);
    float f[RUN_INC];
    #pragma unroll
    for (int i = 0; i < RUN_INC / 4; ++i) {
        const float4 v = frow[i];
        f[4 * i + 0] = v.x;
        f[4 * i + 1] = v.y;
        f[4 * i + 2] = v.z;
        f[4 * i + 3] = v.w;
    }

    float acc[RUN_OUTC];
    #pragma unroll
    for (int o = 0; o < RUN_OUTC; ++o) acc[o] = 0.0f;

    // 48x48 MAC; W reads wave-uniform -> LDS broadcast (conflict-free)
    #pragma unroll 4
    for (int i = 0; i < RUN_INC; ++i) {
        const float fi = f[i];
        const float4* __restrict__ w4 = (const float4*)(&W[i][0]); // 192B rows, 16B-aligned
        #pragma unroll
        for (int o4 = 0; o4 < RUN_OUTC / 4; ++o4) {
            const float4 w = w4[o4];
            acc[4 * o4 + 0] = fmaf(fi, w.x, acc[4 * o4 + 0]);
            acc[4 * o4 + 1] = fmaf(fi, w.y, acc[4 * o4 + 1]);
            acc[4 * o4 + 2] = fmaf(fi, w.z, acc[4 * o4 + 2]);
            acc[4 * o4 + 3] = fmaf(fi, w.w, acc[4 * o4 + 3]);
        }
    }

    float* __restrict__ orow = out + (size_t)out_row * RUN_OUTC;
    #pragma unroll
    for (int o = 0; o < RUN_OUTC; ++o) {
        unsafeAtomicAdd(orow + o, acc[o]);   // native global_atomic_add_f32
    }
}

extern "C" void kernel_launch(void* const* d_in, const int* in_sizes, int n_in,
                              void* d_out, int out_size, void* d_ws, size_t ws_size,
                              hipStream_t stream) {
    const float* features = (const float*)d_in[0];
    const float* kernel_w = (const float*)d_in[1];
    const int*   in_idx   = (const int*)d_in[2];
    const int*   out_idx  = (const int*)d_in[3];
    const int*   mask     = (const int*)d_in[4];
    float*       out      = (float*)d_out;

    // d_out is poisoned 0xAA before every timed call -> zero the scatter target
    hipMemsetAsync(out, 0, (size_t)out_size * sizeof(float), stream);

    dim3 grid((MPAIR + 255) / 256, K_RUN);
    dim3 block(256);
    conv_gather_scatter<<<grid, block, 0, stream>>>(
        features, kernel_w, in_idx, out_idx, mask, out);
}

// Round 3
// 1114.526 us; speedup vs baseline: 4.8630x; 4.8630x over previous
//
#include <hip/hip_runtime.h>
#include <hip/hip_bf16.h>

// Problem constants (match reference)
#define KS_FULL 5
#define INC 64
#define OUTC 64
#define RUN_INC 48
#define RUN_OUTC 48
#define NPTS 200000
#define MPAIR 150000
#define K_RUN 27
#define NPAIRS (K_RUN * MPAIR)                 // 4,050,000
#define NSCAN (NPTS + 1)                       // 200,001
#define SCAN_CHUNK 1024
#define NB1 ((NSCAN + SCAN_CHUNK - 1) / SCAN_CHUNK)   // 196

// d_ws layout (byte offsets)
#define OFF_COUNTS   0u                        // int[200001]
#define OFF_OFFSETS  (1u << 20)                // int[200001]
#define OFF_CURSOR   (2u << 20)                // int[200000]
#define OFF_BSUMS    (3u << 20)                // int[NB1]
#define OFF_WBF      ((3u << 20) + 65536u)     // ushort[27*6*48*8] = 124,416 B
#define OFF_SORTED   (4u << 20)                // int[NPAIRS] = 16.2 MB
#define WS_NEED      ((size_t)OFF_SORTED + (size_t)NPAIRS * 4)

#define WBF_USHORTS (K_RUN * 6 * RUN_OUTC * 8) // 62,208
#define WBF_BYTES   (WBF_USHORTS * 2)          // 124,416

// ---------------------------------------------------------------------------
// prep: extract 27x48x48 center sub-kernel, convert to bf16, store in the
// LDS-friendly layout [k][ic=i/8][o][j=i%8] (16B per (k,ic,o) -> ds_read_b128)
__global__ __launch_bounds__(256) void prep_wbf(
    const float* __restrict__ kernel, ushort* __restrict__ wbf)
{
    int t = blockIdx.x * 256 + threadIdx.x;
    if (t >= K_RUN * RUN_INC * RUN_OUTC) return;
    int k = t / (RUN_INC * RUN_OUTC);
    int r = t - k * (RUN_INC * RUN_OUTC);
    int i = r / RUN_OUTC;
    int o = r - i * RUN_OUTC;
    int a = k / 9, b = (k / 3) % 3, c = k % 3;
    int kf = (a + 1) * (KS_FULL * KS_FULL) + (b + 1) * KS_FULL + (c + 1);
    float v = kernel[(size_t)kf * (INC * OUTC) + i * OUTC + o];
    __hip_bfloat16 h = __float2bfloat16(v);
    wbf[(((k * 6 + (i >> 3)) * RUN_OUTC + o) << 3) + (i & 7)] =
        *reinterpret_cast<ushort*>(&h);
}

// ---------------------------------------------------------------------------
// hist: count active pairs per output row (int atomics, L2-resident 800KB)
__global__ __launch_bounds__(256) void hist_kernel(
    const int* __restrict__ out_idx, const int* __restrict__ mask,
    int* __restrict__ counts)
{
    int m = blockIdx.x * 256 + threadIdx.x;
    if (m >= MPAIR) return;
    int pair = blockIdx.y * MPAIR + m;
    if (mask[pair]) atomicAdd(&counts[out_idx[pair]], 1);
}

// ---------------------------------------------------------------------------
// scan1: per-1024-chunk exclusive scan; blockSums out
__global__ __launch_bounds__(256) void scan1_kernel(
    const int* __restrict__ counts, int* __restrict__ offsets,
    int* __restrict__ bsums)
{
    __shared__ int sh[2][256];
    int b = blockIdx.x, t = threadIdx.x;
    int gbase = b * SCAN_CHUNK + t * 4;
    int v0 = (gbase + 0 < NSCAN) ? counts[gbase + 0] : 0;
    int v1 = (gbase + 1 < NSCAN) ? counts[gbase + 1] : 0;
    int v2 = (gbase + 2 < NSCAN) ? counts[gbase + 2] : 0;
    int v3 = (gbase + 3 < NSCAN) ? counts[gbase + 3] : 0;
    int tsum = v0 + v1 + v2 + v3;
    sh[0][t] = tsum;
    __syncthreads();
    int src = 0;
    for (int d = 1; d < 256; d <<= 1) {
        int dst = src ^ 1;
        sh[dst][t] = sh[src][t] + ((t >= d) ? sh[src][t - d] : 0);
        __syncthreads();
        src = dst;
    }
    int incl = sh[src][t];
    int excl = incl - tsum;
    if (t == 255) bsums[b] = incl;
    int run = excl;
    if (gbase + 0 < NSCAN) { offsets[gbase + 0] = run; } run += v0;
    if (gbase + 1 < NSCAN) { offsets[gbase + 1] = run; } run += v1;
    if (gbase + 2 < NSCAN) { offsets[gbase + 2] = run; } run += v2;
    if (gbase + 3 < NSCAN) { offsets[gbase + 3] = run; }
}

// scan2: exclusive scan of the NB1 block sums (single block)
__global__ __launch_bounds__(256) void scan2_kernel(int* __restrict__ bsums)
{
    __shared__ int sh[2][256];
    int t = threadIdx.x;
    int v = (t < NB1) ? bsums[t] : 0;
    sh[0][t] = v;
    __syncthreads();
    int src = 0;
    for (int d = 1; d < 256; d <<= 1) {
        int dst = src ^ 1;
        sh[dst][t] = sh[src][t] + ((t >= d) ? sh[src][t - d] : 0);
        __syncthreads();
        src = dst;
    }
    if (t < NB1) bsums[t] = sh[src][t] - v;  // exclusive
}

// scan3: add block offsets; produce cursor copy
__global__ __launch_bounds__(256) void scan3_kernel(
    int* __restrict__ offsets, const int* __restrict__ bsums,
    int* __restrict__ cursor)
{
    int gi = blockIdx.x * 256 + threadIdx.x;
    if (gi < NSCAN) {
        int v = offsets[gi] + bsums[gi >> 10];
        offsets[gi] = v;
        if (gi < NPTS) cursor[gi] = v;
    }
}

// ---------------------------------------------------------------------------
// fill: scatter packed (in_row | k<<18) into row-sorted slots
__global__ __launch_bounds__(256) void fill_kernel(
    const int* __restrict__ in_idx, const int* __restrict__ out_idx,
    const int* __restrict__ mask, int* __restrict__ cursor,
    int* __restrict__ sorted)
{
    int m = blockIdx.x * 256 + threadIdx.x;
    if (m >= MPAIR) return;
    int k = blockIdx.y;
    int pair = k * MPAIR + m;
    if (!mask[pair]) return;
    int row = out_idx[pair];
    int pos = atomicAdd(&cursor[row], 1);
    sorted[pos] = in_idx[pair] | (k << 18);
}

// ---------------------------------------------------------------------------
// accum: one wave per output row; lane = out-channel; all 27 W tiles in LDS
// as bf16, layout [k][ic][o][8] so ds_read_b128 per (pair, ic) is
// bank-conflict-free (8-lane phase covers banks 0..31 exactly once).
#define MAC2(word, i0)                                         \
    {                                                          \
        float lo_ = __uint_as_float((word) << 16);             \
        float hi_ = __uint_as_float((word) & 0xFFFF0000u);     \
        acc = fmaf(lo_, f[(i0)], acc);                         \
        acc = fmaf(hi_, f[(i0) + 1], acc);                     \
    }

__global__ __launch_bounds__(1024) void accum_kernel(
    const float* __restrict__ features, const ushort* __restrict__ wbf,
    const int* __restrict__ offsets, const int* __restrict__ sorted,
    float* __restrict__ out)
{
    extern __shared__ __align__(16) ushort Wlds[];
    // stage 124,416 B (identical linear layout -> plain vectorized copy)
    {
        const uint4* src = (const uint4*)wbf;
        uint4* dst = (uint4*)Wlds;
        for (int i = threadIdx.x; i < WBF_BYTES / 16; i += 1024) dst[i] = src[i];
    }
    __syncthreads();

    const int wid  = threadIdx.x >> 6;
    const int lane = threadIdx.x & 63;
    const int o    = (lane < RUN_OUTC) ? lane : (lane - RUN_OUTC); // dup, no store
    const int gw   = blockIdx.x * 16 + wid;

    for (int row = gw; row < NPTS; row += 256 * 16) {
        const int start = offsets[row];
        const int end   = offsets[row + 1];
        float acc = 0.0f;
        for (int p = start; p < end; ++p) {
            const int e      = sorted[p];          // wave-uniform
            const int in_row = e & 0x3FFFF;
            const int kk     = e >> 18;
            const float4* frow = (const float4*)(features + (size_t)in_row * RUN_INC);
            float f[RUN_INC];
            #pragma unroll
            for (int q = 0; q < RUN_INC / 4; ++q) {
                const float4 v = frow[q];
                f[4 * q + 0] = v.x; f[4 * q + 1] = v.y;
                f[4 * q + 2] = v.z; f[4 * q + 3] = v.w;
            }
            const ushort* wbase = Wlds + (((kk * 6) * RUN_OUTC + o) << 3);
            #pragma unroll
            for (int ic = 0; ic < 6; ++ic) {
                const uint4 w = *(const uint4*)(wbase + ic * (RUN_OUTC * 8));
                MAC2(w.x, ic * 8 + 0)
                MAC2(w.y, ic * 8 + 2)
                MAC2(w.z, ic * 8 + 4)
                MAC2(w.w, ic * 8 + 6)
            }
        }
        if (lane < RUN_OUTC) out[(size_t)row * RUN_OUTC + lane] = acc;
    }
}

// ---------------------------------------------------------------------------
// Fallback (ws too small): R2 atomic kernel
__global__ __launch_bounds__(256) void conv_gather_scatter(
    const float* __restrict__ features, const float* __restrict__ kernel,
    const int* __restrict__ in_idx, const int* __restrict__ out_idx,
    const int* __restrict__ mask, float* __restrict__ out)
{
    __shared__ float W[RUN_INC][RUN_OUTC];
    const int k = blockIdx.y;
    const int a = k / 9, b = (k / 3) % 3, c = k % 3;
    const int kf = ((a + 1) * KS_FULL + (b + 1)) * KS_FULL + (c + 1);
    const float* __restrict__ Wsrc = kernel + (size_t)kf * (INC * OUTC);
    for (int e = threadIdx.x; e < RUN_INC * RUN_OUTC; e += 256) {
        const int i = e / RUN_OUTC;
        const int o = e - i * RUN_OUTC;
        W[i][o] = Wsrc[i * OUTC + o];
    }
    __syncthreads();
    const int m = blockIdx.x * 256 + threadIdx.x;
    if (m >= MPAIR) return;
    const int pair = k * MPAIR + m;
    if (!mask[pair]) return;
    const int in_row = in_idx[pair], out_row = out_idx[pair];
    const float4* __restrict__ frow = (const float4*)(features + (size_t)in_row * RUN_INC);
    float f[RUN_INC];
    #pragma unroll
    for (int i = 0; i < RUN_INC / 4; ++i) {
        const float4 v = frow[i];
        f[4 * i] = v.x; f[4 * i + 1] = v.y; f[4 * i + 2] = v.z; f[4 * i + 3] = v.w;
    }
    float acc[RUN_OUTC];
    #pragma unroll
    for (int o = 0; o < RUN_OUTC; ++o) acc[o] = 0.0f;
    #pragma unroll 4
    for (int i = 0; i < RUN_INC; ++i) {
        const float fi = f[i];
        const float4* __restrict__ w4 = (const float4*)(&W[i][0]);
        #pragma unroll
        for (int o4 = 0; o4 < RUN_OUTC / 4; ++o4) {
            const float4 w = w4[o4];
            acc[4 * o4 + 0] = fmaf(fi, w.x, acc[4 * o4 + 0]);
            acc[4 * o4 + 1] = fmaf(fi, w.y, acc[4 * o4 + 1]);
            acc[4 * o4 + 2] = fmaf(fi, w.z, acc[4 * o4 + 2]);
            acc[4 * o4 + 3] = fmaf(fi, w.w, acc[4 * o4 + 3]);
        }
    }
    float* __restrict__ orow = out + (size_t)out_row * RUN_OUTC;
    #pragma unroll
    for (int o = 0; o < RUN_OUTC; ++o) unsafeAtomicAdd(orow + o, acc[o]);
}

// ---------------------------------------------------------------------------
extern "C" void kernel_launch(void* const* d_in, const int* in_sizes, int n_in,
                              void* d_out, int out_size, void* d_ws, size_t ws_size,
                              hipStream_t stream) {
    const float* features = (const float*)d_in[0];
    const float* kernel_w = (const float*)d_in[1];
    const int*   in_idx   = (const int*)d_in[2];
    const int*   out_idx  = (const int*)d_in[3];
    const int*   mask     = (const int*)d_in[4];
    float*       out      = (float*)d_out;

    if (ws_size < WS_NEED) {
        // fallback: R2 atomic path
        hipMemsetAsync(out, 0, (size_t)out_size * sizeof(float), stream);
        dim3 grid((MPAIR + 255) / 256, K_RUN);
        conv_gather_scatter<<<grid, 256, 0, stream>>>(
            features, kernel_w, in_idx, out_idx, mask, out);
        return;
    }

    char* ws = (char*)d_ws;
    int*    counts  = (int*)(ws + OFF_COUNTS);
    int*    offsets = (int*)(ws + OFF_OFFSETS);
    int*    cursor  = (int*)(ws + OFF_CURSOR);
    int*    bsums   = (int*)(ws + OFF_BSUMS);
    ushort* wbf     = (ushort*)(ws + OFF_WBF);
    int*    sorted  = (int*)(ws + OFF_SORTED);

    hipMemsetAsync(counts, 0, (size_t)NSCAN * sizeof(int), stream);

    prep_wbf<<<(K_RUN * RUN_INC * RUN_OUTC + 255) / 256, 256, 0, stream>>>(
        kernel_w, wbf);

    dim3 pgrid((MPAIR + 255) / 256, K_RUN);
    hist_kernel<<<pgrid, 256, 0, stream>>>(out_idx, mask, counts);

    scan1_kernel<<<NB1, 256, 0, stream>>>(counts, offsets, bsums);
    scan2_kernel<<<1, 256, 0, stream>>>(bsums);
    scan3_kernel<<<(NSCAN + 255) / 256, 256, 0, stream>>>(offsets, bsums, cursor);

    fill_kernel<<<pgrid, 256, 0, stream>>>(in_idx, out_idx, mask, cursor, sorted);

    accum_kernel<<<256, 1024, WBF_BYTES, stream>>>(
        features, wbf, offsets, sorted, out);
}